// Round 8
// baseline (62.759 us; speedup 1.0000x reference)
//
#include <hip/hip_runtime.h>
#include <hip/hip_bf16.h>

#define BATCH 16
#define CHAN  256
#define HW    16384
#define NCLS  6

typedef float  f32x4 __attribute__((ext_vector_type(4)));
typedef int    i32x4 __attribute__((ext_vector_type(4)));

// One single-wave block (64 threads) per (b,c). 256 px/thread as 4 outer
// iterations x 16 fully-unrolled {float4 x, int4 gt} loads (the proven
// 16-deep load window). Single wave => no LDS reduce, no __syncthreads;
// one butterfly per 16384 px instead of four.
__global__ __launch_bounds__(64)
void gt2center_kernel(const float* __restrict__ x,
                      const int*   __restrict__ gt,
                      float*       __restrict__ out) {
    const int bc = blockIdx.x;          // b*CHAN + c
    const int b  = bc >> 8;             // CHAN == 256
    const int c  = bc & 255;
    const float* __restrict__ xp = x  + (size_t)bc * HW;
    const int*   __restrict__ gp = gt + (size_t)b  * HW;
    const int t = threadIdx.x;          // 0..63

    float s[NCLS];
    int   cnt[NCLS];
#pragma unroll
    for (int k = 0; k < NCLS; ++k) { s[k] = 0.0f; cnt[k] = 0; }

    for (int o = 0; o < 4; ++o) {
        const int base = o * 4096 + t * 4;
#pragma unroll
        for (int i = 0; i < 16; ++i) {
            const int n = base + i * 256;
            const f32x4 v = *reinterpret_cast<const f32x4*>(xp + n);
            const i32x4 L = *reinterpret_cast<const i32x4*>(gp + n);
#pragma unroll
            for (int k = 0; k < NCLS; ++k) {
                s[k] += (L.x == k) ? v.x : 0.0f;
                s[k] += (L.y == k) ? v.y : 0.0f;
                s[k] += (L.z == k) ? v.z : 0.0f;
                s[k] += (L.w == k) ? v.w : 0.0f;
                cnt[k] += (L.x == k) + (L.y == k) + (L.z == k) + (L.w == k);
            }
        }
    }

    // single 64-lane butterfly reduce
#pragma unroll
    for (int off = 32; off >= 1; off >>= 1) {
#pragma unroll
        for (int k = 0; k < NCLS; ++k) {
            s[k]   += __shfl_xor(s[k],   off, 64);
            cnt[k] += __shfl_xor(cnt[k], off, 64);
        }
    }

    if (t < NCLS) {
        const float d = (cnt[t] > 1) ? (float)cnt[t] : 1.0f;
        out[((size_t)b * NCLS + t) * CHAN + c] = s[t] / d;
    }
}

extern "C" void kernel_launch(void* const* d_in, const int* in_sizes, int n_in,
                              void* d_out, int out_size, void* d_ws, size_t ws_size,
                              hipStream_t stream) {
    const float* x   = (const float*)d_in[0];
    const int*   gt  = (const int*)d_in[1];
    float*       out = (float*)d_out;
    gt2center_kernel<<<BATCH * CHAN, 64, 0, stream>>>(x, gt, out);
}

// Round 9
// 49.604 us; speedup vs baseline: 1.2652x; 1.2652x over previous
//
#include <hip/hip_runtime.h>
#include <hip/hip_bf16.h>

#define BATCH 16
#define CHAN  256
#define HW    16384
#define NCLS  6

// One block per (b,c). 256 threads. Each thread processes 64 pixels as
// 16 fully-unrolled iterations of float4/int4 (deep load window = the
// proven engine; every structural variant regressed vs this).
// Per-class select-accumulate into registers, wave butterfly reduce,
// cross-wave LDS reduce, write out[b][k][c].
__global__ __launch_bounds__(256)
void gt2center_kernel(const float* __restrict__ x,
                      const int*   __restrict__ gt,
                      float*       __restrict__ out) {
    const int bc = blockIdx.x;          // b*CHAN + c
    const int b  = bc >> 8;             // CHAN == 256
    const int c  = bc & 255;
    const float* __restrict__ xp = x  + (size_t)bc * HW;
    const int*   __restrict__ gp = gt + (size_t)b  * HW;
    const int t = threadIdx.x;

    float s[NCLS];
    int   cnt[NCLS];
#pragma unroll
    for (int k = 0; k < NCLS; ++k) { s[k] = 0.0f; cnt[k] = 0; }

#pragma unroll
    for (int i = 0; i < 16; ++i) {
        const int n = i * 1024 + t * 4;
        const float4 v = *reinterpret_cast<const float4*>(xp + n);
        const int4   L = *reinterpret_cast<const int4*>(gp + n);
#pragma unroll
        for (int k = 0; k < NCLS; ++k) {
            s[k] += (L.x == k) ? v.x : 0.0f;
            s[k] += (L.y == k) ? v.y : 0.0f;
            s[k] += (L.z == k) ? v.z : 0.0f;
            s[k] += (L.w == k) ? v.w : 0.0f;
            cnt[k] += (L.x == k) + (L.y == k) + (L.z == k) + (L.w == k);
        }
    }

    // wave (64-lane) butterfly reduce
#pragma unroll
    for (int off = 32; off >= 1; off >>= 1) {
#pragma unroll
        for (int k = 0; k < NCLS; ++k) {
            s[k]   += __shfl_xor(s[k],   off, 64);
            cnt[k] += __shfl_xor(cnt[k], off, 64);
        }
    }

    __shared__ float ls[4][NCLS];
    __shared__ int   lc[4][NCLS];
    const int wave = t >> 6, lane = t & 63;
    if (lane == 0) {
#pragma unroll
        for (int k = 0; k < NCLS; ++k) { ls[wave][k] = s[k]; lc[wave][k] = cnt[k]; }
    }
    __syncthreads();

    if (t < NCLS) {
        const float ssum = ls[0][t] + ls[1][t] + ls[2][t] + ls[3][t];
        const int   csum = lc[0][t] + lc[1][t] + lc[2][t] + lc[3][t];
        const float d = (csum > 1) ? (float)csum : 1.0f;
        out[((size_t)b * NCLS + t) * CHAN + c] = ssum / d;
    }
}

extern "C" void kernel_launch(void* const* d_in, const int* in_sizes, int n_in,
                              void* d_out, int out_size, void* d_ws, size_t ws_size,
                              hipStream_t stream) {
    const float* x   = (const float*)d_in[0];
    const int*   gt  = (const int*)d_in[1];
    float*       out = (float*)d_out;
    gt2center_kernel<<<BATCH * CHAN, 256, 0, stream>>>(x, gt, out);
}